// Round 14
// baseline (270.884 us; speedup 1.0000x reference)
//
#include <hip/hip_runtime.h>
#include <math.h>

#define D 64
#define CAP 64     // per-node bucket: 64 edges; P(deg>64)~5e-16 for Poisson(16)
#define NBB 128    // blocks doing the bin pass (64 was a -20us regression, R13)
#define NPB 64     // nodes per bin (dst >> 6); 1563 bins for N=100K
#define NBINMAX 2048

typedef __attribute__((ext_vector_type(8))) short bf16x8;
typedef __attribute__((ext_vector_type(4))) float f32x4;

__device__ __forceinline__ float lrelu(float x, float s) { return x > 0.f ? x : s * x; }

// f32 -> bf16 round-to-nearest-even
__device__ __forceinline__ unsigned f2bf(float f) {
    unsigned b = __builtin_bit_cast(unsigned, f);
    return (b + 0x7fffu + ((b >> 16) & 1u)) >> 16;
}
__device__ __forceinline__ float bflo(unsigned u) { return __builtin_bit_cast(float, u << 16); }
__device__ __forceinline__ float bfhi(unsigned u) { return __builtin_bit_cast(float, u & 0xffff0000u); }

// Pre-pack W1/W2 into MFMA B-fragment order: replaces the per-wave preamble of
// 64 strided scalar loads+cvts with 8 coalesced 16B loads.
// wt[(kc*4+jb)*64 + lane] = uint4 of 8 bf16; elem e = W[(kc*32+(lane>>4)*8+e)*D + jb*16+(lane&15)]
__global__ __launch_bounds__(256) void k_wprep(const float* __restrict__ W1,
        const float* __restrict__ W2, uint4* __restrict__ wt1, uint4* __restrict__ wt2) {
    int ei = ((blockIdx.x & 1) << 8) + threadIdx.x;   // 0..511
    const float* W = (blockIdx.x < 2) ? W1 : W2;
    uint4* dst = (blockIdx.x < 2) ? wt1 : wt2;
    int lane = ei & 63, kcjb = ei >> 6;
    int kc = kcjb >> 2, jb = kcjb & 3;
    int row16 = lane & 15, kg = lane >> 4;
    unsigned s[4];
    #pragma unroll
    for (int p = 0; p < 4; ++p) {
        unsigned lo = f2bf(W[(kc * 32 + kg * 8 + 2 * p + 0) * D + jb * 16 + row16]);
        unsigned hi = f2bf(W[(kc * 32 + kg * 8 + 2 * p + 1) * D + jb * 16 + row16]);
        s[p] = lo | (hi << 16);
    }
    dst[ei] = make_uint4(s[0], s[1], s[2], s[3]);
}

// MFMA mm body: [N x 64] @ [64 x 64] on matrix cores.
// Layouts (cdna4_isa §10, m89-verified C/D):
//   A: row=lane&15, k=(lane>>4)*8+e   B: col=lane&15, k=(lane>>4)*8+e
//   C/D: col=lane&15, row=(lane>>4)*4+reg
__device__ __forceinline__ void mm_mfma(const float* __restrict__ xin,
        const uint4* __restrict__ wt, const float* __restrict__ a_src, const float* __restrict__ a_dst,
        const float* __restrict__ bn_sum, const float* __restrict__ bn_sumsq,
        const float* __restrict__ gamma, const float* __restrict__ beta, int apply_bn,
        unsigned* __restrict__ hb, float* __restrict__ ssrc, float* __restrict__ sdst,
        int N, int wave, int nwaves, int lane) {
    int row16 = lane & 15;     // A-row within tile / C-col within jb block
    int kg = lane >> 4;        // k-group 0..3

    bf16x8 wf[2][4];
    #pragma unroll
    for (int kc = 0; kc < 2; ++kc)
        #pragma unroll
        for (int jb = 0; jb < 4; ++jb)
            wf[kc][jb] = __builtin_bit_cast(bf16x8, wt[(kc * 4 + jb) * 64 + lane]);

    float asv[4], adv[4];
    #pragma unroll
    for (int jb = 0; jb < 4; ++jb) {
        asv[jb] = a_src[jb * 16 + row16];
        adv[jb] = a_dst[jb * 16 + row16];
    }
    // BN scale/shift for the 16 K-columns this lane loads (L2-hot 256B region)
    float sc[2][8], sh[2][8];
    if (apply_bn) {
        #pragma unroll
        for (int kc = 0; kc < 2; ++kc)
            #pragma unroll
            for (int e = 0; e < 8; ++e) {
                int c = kc * 32 + kg * 8 + e;
                float mu = bn_sum[c] / (float)N;
                float var = bn_sumsq[c] / (float)N - mu * mu;   // biased var = jnp.var
                float rs = rsqrtf(var + 1e-5f);
                sc[kc][e] = rs * gamma[c];
                sh[kc][e] = beta[c] - mu * sc[kc][e];
            }
    }

    int ntiles = (N + 15) >> 4;
    for (int t = wave; t < ntiles; t += nwaves) {
        int r0 = t << 4;
        int arow = r0 + row16;
        int arowc = arow < N ? arow : N - 1;      // tail clamp (N%16==0: never taken)
        // A fragments: 8 consecutive fp32 per lane (two float4), BN+act, cvt bf16
        bf16x8 af[2];
        #pragma unroll
        for (int kc = 0; kc < 2; ++kc) {
            const float* p = xin + (size_t)arowc * D + kc * 32 + kg * 8;
            float4 u0 = *(const float4*)p;
            float4 u1 = *(const float4*)(p + 4);
            float v[8] = {u0.x, u0.y, u0.z, u0.w, u1.x, u1.y, u1.z, u1.w};
            bf16x8 f;
            #pragma unroll
            for (int e = 0; e < 8; ++e) {
                float vv = v[e];
                if (apply_bn) { vv = vv * sc[kc][e] + sh[kc][e]; vv = vv > 0.f ? vv : 0.01f * vv; }
                f[e] = (short)f2bf(vv);
            }
            af[kc] = f;
        }
        f32x4 acc0 = {0,0,0,0}, acc1 = {0,0,0,0}, acc2 = {0,0,0,0}, acc3 = {0,0,0,0};
        acc0 = __builtin_amdgcn_mfma_f32_16x16x32_bf16(af[0], wf[0][0], acc0, 0, 0, 0);
        acc1 = __builtin_amdgcn_mfma_f32_16x16x32_bf16(af[0], wf[0][1], acc1, 0, 0, 0);
        acc2 = __builtin_amdgcn_mfma_f32_16x16x32_bf16(af[0], wf[0][2], acc2, 0, 0, 0);
        acc3 = __builtin_amdgcn_mfma_f32_16x16x32_bf16(af[0], wf[0][3], acc3, 0, 0, 0);
        acc0 = __builtin_amdgcn_mfma_f32_16x16x32_bf16(af[1], wf[1][0], acc0, 0, 0, 0);
        acc1 = __builtin_amdgcn_mfma_f32_16x16x32_bf16(af[1], wf[1][1], acc1, 0, 0, 0);
        acc2 = __builtin_amdgcn_mfma_f32_16x16x32_bf16(af[1], wf[1][2], acc2, 0, 0, 0);
        acc3 = __builtin_amdgcn_mfma_f32_16x16x32_bf16(af[1], wf[1][3], acc3, 0, 0, 0);

        // epilogue: lane holds C rows kg*4+r (r=0..3), col jb*16+row16
        #pragma unroll
        for (int r = 0; r < 4; ++r) {
            int row = r0 + kg * 4 + r;
            float c0 = acc0[r], c1 = acc1[r], c2 = acc2[r], c3 = acc3[r];
            // hb pack: pair adjacent cols via shfl_xor(1); even row16 lanes store
            float p0 = __shfl_xor(c0, 1, 64);
            float p1 = __shfl_xor(c1, 1, 64);
            float p2 = __shfl_xor(c2, 1, 64);
            float p3 = __shfl_xor(c3, 1, 64);
            if (!(row16 & 1) && row < N) {
                size_t hbase = (size_t)row * 32 + (row16 >> 1);
                hb[hbase + 0]  = f2bf(c0) | (f2bf(p0) << 16);
                hb[hbase + 8]  = f2bf(c1) | (f2bf(p1) << 16);
                hb[hbase + 16] = f2bf(c2) | (f2bf(p2) << 16);
                hb[hbase + 24] = f2bf(c3) | (f2bf(p3) << 16);
            }
            // ssrc/sdst: per-lane partial over jb cols, reduce across the 16-lane col group
            float vs = fmaf(c0, asv[0], fmaf(c1, asv[1], fmaf(c2, asv[2], c3 * asv[3])));
            float vd = fmaf(c0, adv[0], fmaf(c1, adv[1], fmaf(c2, adv[2], c3 * adv[3])));
            #pragma unroll
            for (int off = 1; off <= 8; off <<= 1) {
                vs += __shfl_xor(vs, off, 64);
                vd += __shfl_xor(vd, off, 64);
            }
            if (row16 == 0 && row < N) { ssrc[row] = vs; sdst[row] = vd; }
        }
    }
}

// Pass 1 fused with layer-1 mm.
// Blocks [0,NBB): bin edges by dst>>6 into per-bin regions of `binned`,
//   entries packed 4B: src | dstLocal<<17 (src<2^17, dstLocal<64).
// Blocks [NBB, grid): layer-1 mm (MFMA).
__global__ __launch_bounds__(256) void k_bin_mm1(const int* __restrict__ ei, int E,
        int* __restrict__ bin_ptr, unsigned* __restrict__ binned, int BCAP,
        const float* __restrict__ xin, const uint4* __restrict__ wt,
        const float* __restrict__ a_src, const float* __restrict__ a_dst,
        unsigned* __restrict__ hb, float* __restrict__ ssrc, float* __restrict__ sdst, int N) {
    __shared__ int hist[NBINMAX], cur[NBINMAX];
    int tid = threadIdx.x, lane = tid & 63, wv = tid >> 6;
    if (blockIdx.x < NBB) {
        int nb = (N + NPB - 1) >> 6;
        for (int t = tid; t < nb; t += 256) hist[t] = 0;
        __syncthreads();
        int nq4 = E >> 2;
        int qpb = (nq4 + NBB - 1) / NBB;
        int q0 = blockIdx.x * qpb;
        int q1 = q0 + qpb; if (q1 > nq4) q1 = nq4;
        const int4* s4 = (const int4*)ei;
        const int4* d4 = (const int4*)(ei + E);
        // pass A: LDS histogram over bins (int atomics: native, fast)
        for (int i = q0 + tid; i < q1; i += 256) {
            int4 d = d4[i];
            atomicAdd(&hist[d.x >> 6], 1);
            atomicAdd(&hist[d.y >> 6], 1);
            atomicAdd(&hist[d.z >> 6], 1);
            atomicAdd(&hist[d.w >> 6], 1);
        }
        if (blockIdx.x == 0 && tid < (E & 3)) {
            int dd = ei[E + (nq4 << 2) + tid];
            atomicAdd(&hist[dd >> 6], 1);
        }
        __syncthreads();
        // reserve contiguous slices per bin (device atomics: one per (block,nonempty-bin))
        for (int t = tid; t < nb; t += 256)
            cur[t] = hist[t] ? atomicAdd(&bin_ptr[t], hist[t]) : 0;
        __syncthreads();
        // pass B: place packed edges (dst re-read is L2-hot)
        for (int i = q0 + tid; i < q1; i += 256) {
            int4 s = s4[i];
            int4 d = d4[i];
            int t0 = d.x >> 6, t1 = d.y >> 6, t2 = d.z >> 6, t3 = d.w >> 6;
            int p0 = atomicAdd(&cur[t0], 1);
            int p1 = atomicAdd(&cur[t1], 1);
            int p2 = atomicAdd(&cur[t2], 1);
            int p3 = atomicAdd(&cur[t3], 1);
            if (p0 < BCAP) binned[(size_t)t0 * BCAP + p0] = (unsigned)s.x | ((unsigned)(d.x & 63) << 17);
            if (p1 < BCAP) binned[(size_t)t1 * BCAP + p1] = (unsigned)s.y | ((unsigned)(d.y & 63) << 17);
            if (p2 < BCAP) binned[(size_t)t2 * BCAP + p2] = (unsigned)s.z | ((unsigned)(d.z & 63) << 17);
            if (p3 < BCAP) binned[(size_t)t3 * BCAP + p3] = (unsigned)s.w | ((unsigned)(d.w & 63) << 17);
        }
        if (blockIdx.x == 0 && tid < (E & 3)) {
            int i = (nq4 << 2) + tid;
            int ss = ei[i], dd = ei[E + i];
            int t = dd >> 6;
            int p = atomicAdd(&cur[t], 1);
            if (p < BCAP) binned[(size_t)t * BCAP + p] = (unsigned)ss | ((unsigned)(dd & 63) << 17);
        }
    } else {
        int wave = (blockIdx.x - NBB) * 4 + wv;
        int nwaves = (gridDim.x - NBB) * 4;
        mm_mfma(xin, wt, a_src, a_dst, nullptr, nullptr, nullptr, nullptr, 0,
                hb, ssrc, sdst, N, wave, nwaves, lane);
    }
}

// standalone layer-2 mm (MFMA, BN folded in)
__global__ __launch_bounds__(256) void k_mm_att(const float* __restrict__ xin,
        const uint4* __restrict__ wt, const float* __restrict__ a_src, const float* __restrict__ a_dst,
        const float* __restrict__ bn_sum, const float* __restrict__ bn_sumsq,
        const float* __restrict__ gamma, const float* __restrict__ beta,
        unsigned* __restrict__ hb, float* __restrict__ ssrc, float* __restrict__ sdst, int N) {
    int tid = threadIdx.x, lane = tid & 63, wv = tid >> 6;
    mm_mfma(xin, wt, a_src, a_dst, bn_sum, bn_sumsq, gamma, beta, 1,
            hb, ssrc, sdst, N, blockIdx.x * 4 + wv, gridDim.x * 4, lane);
}

// issue quad q of node's edge list into named register quad P
#define AGG_ISSUE(P, q) { \
    int sA_ = __shfl(sal0.x, (q), 16), sB_ = __shfl(sal0.y, (q), 16); \
    int sC_ = __shfl(sal0.z, (q), 16), sD_ = __shfl(sal0.w, (q), 16); \
    P##A = h2[(size_t)sA_ * 16 + sl]; P##B = h2[(size_t)sB_ * 16 + sl]; \
    P##C = h2[(size_t)sC_ * 16 + sl]; P##D = h2[(size_t)sD_ * 16 + sl]; }

// consume register quad P as quad index i
#define AGG_CONSUME(P, i) { \
    float eA_ = __shfl(e0, (i), 16), eB_ = __shfl(e1, (i), 16); \
    float eC_ = __shfl(e2, (i), 16), eD_ = __shfl(e3, (i), 16); \
    acc.x = fmaf(eA_, bflo(P##A.x), acc.x); acc.y = fmaf(eA_, bfhi(P##A.x), acc.y); \
    acc.z = fmaf(eA_, bflo(P##A.y), acc.z); acc.w = fmaf(eA_, bfhi(P##A.y), acc.w); \
    acc.x = fmaf(eB_, bflo(P##B.x), acc.x); acc.y = fmaf(eB_, bfhi(P##B.x), acc.y); \
    acc.z = fmaf(eB_, bflo(P##B.y), acc.z); acc.w = fmaf(eB_, bfhi(P##B.y), acc.w); \
    acc.x = fmaf(eC_, bflo(P##C.x), acc.x); acc.y = fmaf(eC_, bfhi(P##C.x), acc.y); \
    acc.z = fmaf(eC_, bflo(P##C.y), acc.z); acc.w = fmaf(eC_, bfhi(P##C.y), acc.w); \
    acc.x = fmaf(eD_, bflo(P##D.x), acc.x); acc.y = fmaf(eD_, bfhi(P##D.x), acc.y); \
    acc.z = fmaf(eD_, bflo(P##D.y), acc.z); acc.w = fmaf(eD_, bfhi(P##D.y), acc.w); }

// Aggregation with IN-LDS CSR. Round-14: the CSR is built CHUNK-ORDERED —
// 8 passes over the bin's (L2-hot, ~4KB) edge slice, inserting edges with
// src-chunk c (src>>14, 2MB of hb) in pass c. The gather loop (unchanged)
// then walks hb in ~2MB ascending windows; since all resident blocks follow
// the same build->gather schedule, the grid's instantaneous working set is
// ~2 chunks ~ per-XCD L2 (4MB) instead of uniform-random over 12.8MB. The
// 86MB of L2-miss traffic is compulsory; its ORDER was the 68us (random-
// service rate ~1.3TB/s). mode 0: out = agg/z + bias, accumulate BN sums.
// mode 1: out = 0.5*(x + agg/z + bias)
__global__ __launch_bounds__(256) void k_agg(const unsigned* __restrict__ binned,
        const int* __restrict__ bin_ptr, int BCAP,
        const float* __restrict__ ssrc, const float* __restrict__ sdst,
        const unsigned* __restrict__ hb, const float* __restrict__ bias,
        const float* __restrict__ x, float* __restrict__ out,
        float* __restrict__ bn_sum, float* __restrict__ bn_sumsq, int mode, int N) {
    __shared__ int colL[NPB][CAP];     // 16KB bucket CSR
    __shared__ int cntL[NPB];
    __shared__ float ssL[NPB], sdL[NPB];
    __shared__ float sbn1[D], sbn2[D];
    int tid = threadIdx.x;
    int sl = tid & 15;                 // lane within sub-group; covers cols 4sl..4sl+3
    int g = tid >> 4;                  // sub-group 0..15
    int b = blockIdx.x;
    int n0 = b << 6;

    if (tid < NPB) {
        cntL[tid] = 0;
        int nd = n0 + tid;
        ssL[tid] = (nd < N) ? ssrc[nd] : 0.f;
        sdL[tid] = (nd < N) ? sdst[nd] : 0.f;
    }
    if (mode == 0 && tid < D) { sbn1[tid] = 0.f; sbn2[tid] = 0.f; }
    __syncthreads();

    // build LDS CSR in src-chunk order (8 scans of the L2-hot slice)
    int m = bin_ptr[b]; if (m > BCAP) m = BCAP;
    {
        const unsigned* base = binned + (size_t)b * BCAP;
        for (int c = 0; c < 8; ++c) {
            for (int i = tid; i < m; i += 256) {
                unsigned e = base[i];
                int src = (int)(e & 0x1FFFFu);
                if ((src >> 14) == c) {
                    int dl = (int)(e >> 17);
                    int k = atomicAdd(&cntL[dl], 1);
                    if (k < CAP) colL[dl][k] = src;
                }
            }
            __syncthreads();    // chunk c fully inserted before c+1 begins
        }
    }

    const uint2* h2 = (const uint2*)hb;           // row = 16 uint2
    float4 s1 = make_float4(0, 0, 0, 0), s2 = make_float4(0, 0, 0, 0);

    // read node d's sal quad from LDS (clamped lanes -> valid node id)
    auto loadSal = [&](int d, int& dg, int4& sal) {
        int dgl = cntL[d]; if (dgl > CAP) dgl = CAP;
        int4 c = ((const int4*)colL[d])[sl];      // 16B-aligned, conflict-free
        int eb = sl << 2;
        int nd = n0 + d;
        int self = (nd < N) ? nd : 0;
        sal.x = (eb + 0 < dgl) ? c.x : self;
        sal.y = (eb + 1 < dgl) ? c.y : self;
        sal.z = (eb + 2 < dgl) ? c.z : self;
        sal.w = (eb + 3 < dgl) ? c.w : self;
        dg = dgl;
    };

    // sub-group g handles local nodes g, g+16, g+32, g+48
    int dg0; int4 sal0;
    loadSal(g, dg0, sal0);
    float4 g0;
    g0.x = ssrc[sal0.x]; g0.y = ssrc[sal0.y];
    g0.z = ssrc[sal0.z]; g0.w = ssrc[sal0.w];

    #pragma unroll
    for (int idx = 0; idx < 4; ++idx) {
        int d = g + (idx << 4);
        int nd = n0 + d;
        int ndc = (nd < N) ? nd : 0;
        // ---- issue current node's self row + quads 0..2 ----
        uint2 hv = h2[(size_t)ndc * 16 + sl];
        int Q = dg0 > 0 ? ((dg0 + 3) >> 2) : 1;
        uint2 p0A, p0B, p0C, p0D, p1A, p1B, p1C, p1D, p2A, p2B, p2C, p2D;
        AGG_ISSUE(p0, 0)
        if (Q > 1) AGG_ISSUE(p1, 1)
        if (Q > 2) AGG_ISSUE(p2, 2)

        // ---- prep next node: sal from LDS (instant) + issue its g-gathers ----
        int dg1 = 0; int4 sal1 = make_int4(0, 0, 0, 0);
        float4 g1 = make_float4(0, 0, 0, 0);
        if (idx < 3) {
            loadSal(d + 16, dg1, sal1);
            g1.x = ssrc[sal1.x]; g1.y = ssrc[sal1.y];
            g1.z = ssrc[sal1.z]; g1.w = ssrc[sal1.w];
        }

        // ---- e/z from g0 (gathers issued one node earlier) ----
        float sdn = sdL[d];
        int eb = sl << 2;
        float e0 = (eb + 0 < dg0) ? __expf(lrelu(g0.x + sdn, 0.2f)) : 0.f;
        float e1 = (eb + 1 < dg0) ? __expf(lrelu(g0.y + sdn, 0.2f)) : 0.f;
        float e2 = (eb + 2 < dg0) ? __expf(lrelu(g0.z + sdn, 0.2f)) : 0.f;
        float e3 = (eb + 3 < dg0) ? __expf(lrelu(g0.w + sdn, 0.2f)) : 0.f;
        float z = (e0 + e1) + (e2 + e3);
        #pragma unroll
        for (int off = 1; off <= 8; off <<= 1) z += __shfl_xor(z, off, 64);
        float es = __expf(lrelu(ssL[d] + sdn, 0.2f));
        z += es;
        float4 acc;
        acc.x = es * bflo(hv.x); acc.y = es * bfhi(hv.x);
        acc.z = es * bflo(hv.y); acc.w = es * bfhi(hv.y);

        // ---- depth-3 pipelined quad loop (rotating named quads) ----
        int i = 0;
        while (true) {
            AGG_CONSUME(p0, i)
            if (i + 3 < Q) AGG_ISSUE(p0, i + 3)
            if (++i >= Q) break;
            AGG_CONSUME(p1, i)
            if (i + 3 < Q) AGG_ISSUE(p1, i + 3)
            if (++i >= Q) break;
            AGG_CONSUME(p2, i)
            if (i + 3 < Q) AGG_ISSUE(p2, i + 3)
            if (++i >= Q) break;
        }

        // epilogue — no cross-lane reduce; all 16 lanes store
        if (nd < N) {
            float inv = 1.f / z;
            float4 b4 = ((const float4*)bias)[sl];
            float4 v;
            v.x = acc.x * inv + b4.x; v.y = acc.y * inv + b4.y;
            v.z = acc.z * inv + b4.z; v.w = acc.w * inv + b4.w;
            if (mode == 0) {
                ((float4*)out)[(size_t)nd * 16 + sl] = v;
                s1.x += v.x; s1.y += v.y; s1.z += v.z; s1.w += v.w;
                s2.x += v.x * v.x; s2.y += v.y * v.y;
                s2.z += v.z * v.z; s2.w += v.w * v.w;
            } else {
                float4 xv = ((const float4*)x)[(size_t)nd * 16 + sl];
                v.x = 0.5f * (xv.x + v.x); v.y = 0.5f * (xv.y + v.y);
                v.z = 0.5f * (xv.z + v.z); v.w = 0.5f * (xv.w + v.w);
                ((float4*)out)[(size_t)nd * 16 + sl] = v;
            }
        }
        // shift node pipeline
        dg0 = dg1; sal0 = sal1; g0 = g1;
    }
    if (mode == 0) {
        int c = sl * 4;       // block-level epilogue only: 16 ops/thread once per block
        atomicAdd(&sbn1[c + 0], s1.x); atomicAdd(&sbn1[c + 1], s1.y);
        atomicAdd(&sbn1[c + 2], s1.z); atomicAdd(&sbn1[c + 3], s1.w);
        atomicAdd(&sbn2[c + 0], s2.x); atomicAdd(&sbn2[c + 1], s2.y);
        atomicAdd(&sbn2[c + 2], s2.z); atomicAdd(&sbn2[c + 3], s2.w);
        __syncthreads();
        if (tid < D) {
            atomicAdd(&bn_sum[tid], sbn1[tid]);
            atomicAdd(&bn_sumsq[tid], sbn2[tid]);
        }
    }
}

extern "C" void kernel_launch(void* const* d_in, const int* in_sizes, int n_in,
                              void* d_out, int out_size, void* d_ws, size_t ws_size,
                              hipStream_t stream) {
    const float* x     = (const float*)d_in[0];
    const float* W1    = (const float*)d_in[1];
    const float* as1   = (const float*)d_in[2];
    const float* ad1   = (const float*)d_in[3];
    const float* b1    = (const float*)d_in[4];
    const float* gamma = (const float*)d_in[5];
    const float* beta  = (const float*)d_in[6];
    const float* W2    = (const float*)d_in[7];
    const float* as2   = (const float*)d_in[8];
    const float* ad2   = (const float*)d_in[9];
    const float* b2    = (const float*)d_in[10];
    const int*   ei    = (const int*)d_in[11];
    int N = in_sizes[0] / D;
    int E = in_sizes[11] / 2;
    float* out = (float*)d_out;          // layer-1 output buffer (fp32), then final

    float* ws = (float*)d_ws;
    unsigned* hb = (unsigned*)ws;                 // bf16-packed h: N*32 uints (12.8MB)
    float* ssrc = (float*)(hb + (size_t)N * 32);
    float* sdst = ssrc + N;
    int* binp   = (int*)(sdst + N);               // NBINMAX bin totals (memset)
    float* bn   = (float*)(binp + NBINMAX);       // 128: sum(64) | sumsq(64) (memset, contiguous)
    uint4* wt1  = (uint4*)(bn + 128);             // 512 uint4 = 8KB MFMA-packed W1
    uint4* wt2  = wt1 + 512;                      // 8KB MFMA-packed W2
    unsigned* binned = (unsigned*)(wt2 + 512);    // nb*BCAP packed edges (~9.6MB, in ws:
                                                  // must SURVIVE until agg2 — no d_out alias)

    int nb = (N + NPB - 1) >> 6;                  // 1563 bins for N=100K
    int BCAP = E / nb + (E / nb) / 4 + 256;       // avg + 25% + slack (~16 sigma)

    dim3 blk(256);

    // zero bin totals + bn in one async memset
    hipMemsetAsync(binp, 0, NBINMAX * 4 + 512, stream);

    // ---- prep: pack W1/W2 into MFMA fragment tables (8KB each) ----
    k_wprep<<<4, blk, 0, stream>>>(W1, W2, wt1, wt2);

    // ---- pass 1: bin edges (packed 4B, 64-node bins) fused with layer-1 MFMA mm ----
    k_bin_mm1<<<2048, blk, 0, stream>>>(ei, E, binp, binned, BCAP,
                                        x, wt1, as1, ad1, hb, ssrc, sdst, N);

    // ---- layer 1 aggregate (in-LDS CSR, chunk-ordered gathers) ----
    k_agg<<<nb, blk, 0, stream>>>(binned, binp, BCAP, ssrc, sdst, hb, b1,
                                  nullptr, out, bn, bn + 64, 0, N);

    // ---- layer 2 (MFMA mm with BN folded; final mix fused into agg) ----
    k_mm_att<<<1024, blk, 0, stream>>>(out, wt2, as2, ad2, bn, bn + 64, gamma, beta,
                                       hb, ssrc, sdst, N);
    k_agg<<<nb, blk, 0, stream>>>(binned, binp, BCAP, ssrc, sdst, hb, b2,
                                  x, out, bn, bn + 64, 1, N);
}

// Round 15
// 245.199 us; speedup vs baseline: 1.1048x; 1.1048x over previous
//
#include <hip/hip_runtime.h>
#include <math.h>

#define D 64
#define CAP 64     // per-node bucket: 64 edges; P(deg>64)~5e-16 for Poisson(16)
#define NBB 256    // blocks doing the bin pass: R13 showed bin half scales with NBB
#define NPB 64     // nodes per bin (dst >> 6); 1563 bins for N=100K
#define NBINMAX 2048

typedef __attribute__((ext_vector_type(8))) short bf16x8;
typedef __attribute__((ext_vector_type(4))) float f32x4;

__device__ __forceinline__ float lrelu(float x, float s) { return x > 0.f ? x : s * x; }

// f32 -> bf16 round-to-nearest-even
__device__ __forceinline__ unsigned f2bf(float f) {
    unsigned b = __builtin_bit_cast(unsigned, f);
    return (b + 0x7fffu + ((b >> 16) & 1u)) >> 16;
}
__device__ __forceinline__ float bflo(unsigned u) { return __builtin_bit_cast(float, u << 16); }
__device__ __forceinline__ float bfhi(unsigned u) { return __builtin_bit_cast(float, u & 0xffff0000u); }

// Pre-pack W1/W2 into MFMA B-fragment order (neutral in R14 A/B, kept: free).
// wt[(kc*4+jb)*64 + lane] = uint4 of 8 bf16; elem e = W[(kc*32+(lane>>4)*8+e)*D + jb*16+(lane&15)]
__global__ __launch_bounds__(256) void k_wprep(const float* __restrict__ W1,
        const float* __restrict__ W2, uint4* __restrict__ wt1, uint4* __restrict__ wt2) {
    int ei = ((blockIdx.x & 1) << 8) + threadIdx.x;   // 0..511
    const float* W = (blockIdx.x < 2) ? W1 : W2;
    uint4* dst = (blockIdx.x < 2) ? wt1 : wt2;
    int lane = ei & 63, kcjb = ei >> 6;
    int kc = kcjb >> 2, jb = kcjb & 3;
    int row16 = lane & 15, kg = lane >> 4;
    unsigned s[4];
    #pragma unroll
    for (int p = 0; p < 4; ++p) {
        unsigned lo = f2bf(W[(kc * 32 + kg * 8 + 2 * p + 0) * D + jb * 16 + row16]);
        unsigned hi = f2bf(W[(kc * 32 + kg * 8 + 2 * p + 1) * D + jb * 16 + row16]);
        s[p] = lo | (hi << 16);
    }
    dst[ei] = make_uint4(s[0], s[1], s[2], s[3]);
}

// MFMA mm body: [N x 64] @ [64 x 64] on matrix cores.
// Layouts (cdna4_isa §10, m89-verified C/D):
//   A: row=lane&15, k=(lane>>4)*8+e   B: col=lane&15, k=(lane>>4)*8+e
//   C/D: col=lane&15, row=(lane>>4)*4+reg
__device__ __forceinline__ void mm_mfma(const float* __restrict__ xin,
        const uint4* __restrict__ wt, const float* __restrict__ a_src, const float* __restrict__ a_dst,
        const float* __restrict__ bn_sum, const float* __restrict__ bn_sumsq,
        const float* __restrict__ gamma, const float* __restrict__ beta, int apply_bn,
        unsigned* __restrict__ hb, float* __restrict__ ssrc, float* __restrict__ sdst,
        int N, int wave, int nwaves, int lane) {
    int row16 = lane & 15;     // A-row within tile / C-col within jb block
    int kg = lane >> 4;        // k-group 0..3

    bf16x8 wf[2][4];
    #pragma unroll
    for (int kc = 0; kc < 2; ++kc)
        #pragma unroll
        for (int jb = 0; jb < 4; ++jb)
            wf[kc][jb] = __builtin_bit_cast(bf16x8, wt[(kc * 4 + jb) * 64 + lane]);

    float asv[4], adv[4];
    #pragma unroll
    for (int jb = 0; jb < 4; ++jb) {
        asv[jb] = a_src[jb * 16 + row16];
        adv[jb] = a_dst[jb * 16 + row16];
    }
    // BN scale/shift for the 16 K-columns this lane loads (L2-hot 256B region)
    float sc[2][8], sh[2][8];
    if (apply_bn) {
        #pragma unroll
        for (int kc = 0; kc < 2; ++kc)
            #pragma unroll
            for (int e = 0; e < 8; ++e) {
                int c = kc * 32 + kg * 8 + e;
                float mu = bn_sum[c] / (float)N;
                float var = bn_sumsq[c] / (float)N - mu * mu;   // biased var = jnp.var
                float rs = rsqrtf(var + 1e-5f);
                sc[kc][e] = rs * gamma[c];
                sh[kc][e] = beta[c] - mu * sc[kc][e];
            }
    }

    int ntiles = (N + 15) >> 4;
    for (int t = wave; t < ntiles; t += nwaves) {
        int r0 = t << 4;
        int arow = r0 + row16;
        int arowc = arow < N ? arow : N - 1;      // tail clamp (N%16==0: never taken)
        // A fragments: 8 consecutive fp32 per lane (two float4), BN+act, cvt bf16
        bf16x8 af[2];
        #pragma unroll
        for (int kc = 0; kc < 2; ++kc) {
            const float* p = xin + (size_t)arowc * D + kc * 32 + kg * 8;
            float4 u0 = *(const float4*)p;
            float4 u1 = *(const float4*)(p + 4);
            float v[8] = {u0.x, u0.y, u0.z, u0.w, u1.x, u1.y, u1.z, u1.w};
            bf16x8 f;
            #pragma unroll
            for (int e = 0; e < 8; ++e) {
                float vv = v[e];
                if (apply_bn) { vv = vv * sc[kc][e] + sh[kc][e]; vv = vv > 0.f ? vv : 0.01f * vv; }
                f[e] = (short)f2bf(vv);
            }
            af[kc] = f;
        }
        f32x4 acc0 = {0,0,0,0}, acc1 = {0,0,0,0}, acc2 = {0,0,0,0}, acc3 = {0,0,0,0};
        acc0 = __builtin_amdgcn_mfma_f32_16x16x32_bf16(af[0], wf[0][0], acc0, 0, 0, 0);
        acc1 = __builtin_amdgcn_mfma_f32_16x16x32_bf16(af[0], wf[0][1], acc1, 0, 0, 0);
        acc2 = __builtin_amdgcn_mfma_f32_16x16x32_bf16(af[0], wf[0][2], acc2, 0, 0, 0);
        acc3 = __builtin_amdgcn_mfma_f32_16x16x32_bf16(af[0], wf[0][3], acc3, 0, 0, 0);
        acc0 = __builtin_amdgcn_mfma_f32_16x16x32_bf16(af[1], wf[1][0], acc0, 0, 0, 0);
        acc1 = __builtin_amdgcn_mfma_f32_16x16x32_bf16(af[1], wf[1][1], acc1, 0, 0, 0);
        acc2 = __builtin_amdgcn_mfma_f32_16x16x32_bf16(af[1], wf[1][2], acc2, 0, 0, 0);
        acc3 = __builtin_amdgcn_mfma_f32_16x16x32_bf16(af[1], wf[1][3], acc3, 0, 0, 0);

        // epilogue: lane holds C rows kg*4+r (r=0..3), col jb*16+row16
        #pragma unroll
        for (int r = 0; r < 4; ++r) {
            int row = r0 + kg * 4 + r;
            float c0 = acc0[r], c1 = acc1[r], c2 = acc2[r], c3 = acc3[r];
            // hb pack: pair adjacent cols via shfl_xor(1); even row16 lanes store
            float p0 = __shfl_xor(c0, 1, 64);
            float p1 = __shfl_xor(c1, 1, 64);
            float p2 = __shfl_xor(c2, 1, 64);
            float p3 = __shfl_xor(c3, 1, 64);
            if (!(row16 & 1) && row < N) {
                size_t hbase = (size_t)row * 32 + (row16 >> 1);
                hb[hbase + 0]  = f2bf(c0) | (f2bf(p0) << 16);
                hb[hbase + 8]  = f2bf(c1) | (f2bf(p1) << 16);
                hb[hbase + 16] = f2bf(c2) | (f2bf(p2) << 16);
                hb[hbase + 24] = f2bf(c3) | (f2bf(p3) << 16);
            }
            // ssrc/sdst: per-lane partial over jb cols, reduce across the 16-lane col group
            float vs = fmaf(c0, asv[0], fmaf(c1, asv[1], fmaf(c2, asv[2], c3 * asv[3])));
            float vd = fmaf(c0, adv[0], fmaf(c1, adv[1], fmaf(c2, adv[2], c3 * adv[3])));
            #pragma unroll
            for (int off = 1; off <= 8; off <<= 1) {
                vs += __shfl_xor(vs, off, 64);
                vd += __shfl_xor(vd, off, 64);
            }
            if (row16 == 0 && row < N) { ssrc[row] = vs; sdst[row] = vd; }
        }
    }
}

// Pass 1 fused with layer-1 mm.
// Blocks [0,NBB): bin edges by dst>>6 into per-bin regions of `binned`,
//   entries packed 4B: src | dstLocal<<17 (src<2^17, dstLocal<64).
// Blocks [NBB, grid): layer-1 mm (MFMA — has large slack, donate blocks to bin).
__global__ __launch_bounds__(256) void k_bin_mm1(const int* __restrict__ ei, int E,
        int* __restrict__ bin_ptr, unsigned* __restrict__ binned, int BCAP,
        const float* __restrict__ xin, const uint4* __restrict__ wt,
        const float* __restrict__ a_src, const float* __restrict__ a_dst,
        unsigned* __restrict__ hb, float* __restrict__ ssrc, float* __restrict__ sdst, int N) {
    __shared__ int hist[NBINMAX], cur[NBINMAX];
    int tid = threadIdx.x, lane = tid & 63, wv = tid >> 6;
    if (blockIdx.x < NBB) {
        int nb = (N + NPB - 1) >> 6;
        for (int t = tid; t < nb; t += 256) hist[t] = 0;
        __syncthreads();
        int nq4 = E >> 2;
        int qpb = (nq4 + NBB - 1) / NBB;
        int q0 = blockIdx.x * qpb;
        int q1 = q0 + qpb; if (q1 > nq4) q1 = nq4;
        const int4* s4 = (const int4*)ei;
        const int4* d4 = (const int4*)(ei + E);
        // pass A: LDS histogram over bins (int atomics: native, fast)
        for (int i = q0 + tid; i < q1; i += 256) {
            int4 d = d4[i];
            atomicAdd(&hist[d.x >> 6], 1);
            atomicAdd(&hist[d.y >> 6], 1);
            atomicAdd(&hist[d.z >> 6], 1);
            atomicAdd(&hist[d.w >> 6], 1);
        }
        if (blockIdx.x == 0 && tid < (E & 3)) {
            int dd = ei[E + (nq4 << 2) + tid];
            atomicAdd(&hist[dd >> 6], 1);
        }
        __syncthreads();
        // reserve contiguous slices per bin (device atomics: one per (block,nonempty-bin))
        for (int t = tid; t < nb; t += 256)
            cur[t] = hist[t] ? atomicAdd(&bin_ptr[t], hist[t]) : 0;
        __syncthreads();
        // pass B: place packed edges (dst re-read is L2-hot)
        for (int i = q0 + tid; i < q1; i += 256) {
            int4 s = s4[i];
            int4 d = d4[i];
            int t0 = d.x >> 6, t1 = d.y >> 6, t2 = d.z >> 6, t3 = d.w >> 6;
            int p0 = atomicAdd(&cur[t0], 1);
            int p1 = atomicAdd(&cur[t1], 1);
            int p2 = atomicAdd(&cur[t2], 1);
            int p3 = atomicAdd(&cur[t3], 1);
            if (p0 < BCAP) binned[(size_t)t0 * BCAP + p0] = (unsigned)s.x | ((unsigned)(d.x & 63) << 17);
            if (p1 < BCAP) binned[(size_t)t1 * BCAP + p1] = (unsigned)s.y | ((unsigned)(d.y & 63) << 17);
            if (p2 < BCAP) binned[(size_t)t2 * BCAP + p2] = (unsigned)s.z | ((unsigned)(d.z & 63) << 17);
            if (p3 < BCAP) binned[(size_t)t3 * BCAP + p3] = (unsigned)s.w | ((unsigned)(d.w & 63) << 17);
        }
        if (blockIdx.x == 0 && tid < (E & 3)) {
            int i = (nq4 << 2) + tid;
            int ss = ei[i], dd = ei[E + i];
            int t = dd >> 6;
            int p = atomicAdd(&cur[t], 1);
            if (p < BCAP) binned[(size_t)t * BCAP + p] = (unsigned)ss | ((unsigned)(dd & 63) << 17);
        }
    } else {
        int wave = (blockIdx.x - NBB) * 4 + wv;
        int nwaves = (gridDim.x - NBB) * 4;
        mm_mfma(xin, wt, a_src, a_dst, nullptr, nullptr, nullptr, nullptr, 0,
                hb, ssrc, sdst, N, wave, nwaves, lane);
    }
}

// standalone layer-2 mm (MFMA, BN folded in)
__global__ __launch_bounds__(256) void k_mm_att(const float* __restrict__ xin,
        const uint4* __restrict__ wt, const float* __restrict__ a_src, const float* __restrict__ a_dst,
        const float* __restrict__ bn_sum, const float* __restrict__ bn_sumsq,
        const float* __restrict__ gamma, const float* __restrict__ beta,
        unsigned* __restrict__ hb, float* __restrict__ ssrc, float* __restrict__ sdst, int N) {
    int tid = threadIdx.x, lane = tid & 63, wv = tid >> 6;
    mm_mfma(xin, wt, a_src, a_dst, bn_sum, bn_sumsq, gamma, beta, 1,
            hb, ssrc, sdst, N, blockIdx.x * 4 + wv, gridDim.x * 4, lane);
}

// issue quad q of node's edge list into named register quad P
#define AGG_ISSUE(P, q) { \
    int sA_ = __shfl(sal0.x, (q), 16), sB_ = __shfl(sal0.y, (q), 16); \
    int sC_ = __shfl(sal0.z, (q), 16), sD_ = __shfl(sal0.w, (q), 16); \
    P##A = h2[(size_t)sA_ * 16 + sl]; P##B = h2[(size_t)sB_ * 16 + sl]; \
    P##C = h2[(size_t)sC_ * 16 + sl]; P##D = h2[(size_t)sD_ * 16 + sl]; }

// consume register quad P as quad index i
#define AGG_CONSUME(P, i) { \
    float eA_ = __shfl(e0, (i), 16), eB_ = __shfl(e1, (i), 16); \
    float eC_ = __shfl(e2, (i), 16), eD_ = __shfl(e3, (i), 16); \
    acc.x = fmaf(eA_, bflo(P##A.x), acc.x); acc.y = fmaf(eA_, bfhi(P##A.x), acc.y); \
    acc.z = fmaf(eA_, bflo(P##A.y), acc.z); acc.w = fmaf(eA_, bfhi(P##A.y), acc.w); \
    acc.x = fmaf(eB_, bflo(P##B.x), acc.x); acc.y = fmaf(eB_, bfhi(P##B.x), acc.y); \
    acc.z = fmaf(eB_, bflo(P##B.y), acc.z); acc.w = fmaf(eB_, bfhi(P##B.y), acc.w); \
    acc.x = fmaf(eC_, bflo(P##C.x), acc.x); acc.y = fmaf(eC_, bfhi(P##C.x), acc.y); \
    acc.z = fmaf(eC_, bflo(P##C.y), acc.z); acc.w = fmaf(eC_, bfhi(P##C.y), acc.w); \
    acc.x = fmaf(eD_, bflo(P##D.x), acc.x); acc.y = fmaf(eD_, bfhi(P##D.x), acc.y); \
    acc.z = fmaf(eD_, bflo(P##D.y), acc.z); acc.w = fmaf(eD_, bfhi(P##D.y), acc.w); }

// Aggregation with IN-LDS CSR (R12 single-pass build restored — R14's
// chunk-ordered 8-scan build was -11us/dispatch: blocks drift out of phase,
// no windowing materializes; the ~68.5us random-gather service floor stands).
// mode 0: out = agg/z + bias (fp32), accumulate BN col sums.
// mode 1: out = 0.5*(x + agg/z + bias)
__global__ __launch_bounds__(256) void k_agg(const unsigned* __restrict__ binned,
        const int* __restrict__ bin_ptr, int BCAP,
        const float* __restrict__ ssrc, const float* __restrict__ sdst,
        const unsigned* __restrict__ hb, const float* __restrict__ bias,
        const float* __restrict__ x, float* __restrict__ out,
        float* __restrict__ bn_sum, float* __restrict__ bn_sumsq, int mode, int N) {
    __shared__ int colL[NPB][CAP];     // 16KB bucket CSR
    __shared__ int cntL[NPB];
    __shared__ float ssL[NPB], sdL[NPB];
    __shared__ float sbn1[D], sbn2[D];
    int tid = threadIdx.x;
    int sl = tid & 15;                 // lane within sub-group; covers cols 4sl..4sl+3
    int g = tid >> 4;                  // sub-group 0..15
    int b = blockIdx.x;
    int n0 = b << 6;

    if (tid < NPB) {
        cntL[tid] = 0;
        int nd = n0 + tid;
        ssL[tid] = (nd < N) ? ssrc[nd] : 0.f;
        sdL[tid] = (nd < N) ? sdst[nd] : 0.f;
    }
    if (mode == 0 && tid < D) { sbn1[tid] = 0.f; sbn2[tid] = 0.f; }
    __syncthreads();

    // build LDS CSR (single pass, int LDS atomics — native ds_add_rtn)
    int m = bin_ptr[b]; if (m > BCAP) m = BCAP;
    {
        const unsigned* base = binned + (size_t)b * BCAP;
        for (int i = tid; i < m; i += 256) {
            unsigned e = base[i];
            int dl = (int)(e >> 17);
            int k = atomicAdd(&cntL[dl], 1);
            if (k < CAP) colL[dl][k] = (int)(e & 0x1FFFFu);
        }
    }
    __syncthreads();

    const uint2* h2 = (const uint2*)hb;           // row = 16 uint2
    float4 s1 = make_float4(0, 0, 0, 0), s2 = make_float4(0, 0, 0, 0);

    // read node d's sal quad from LDS (clamped lanes -> valid node id)
    auto loadSal = [&](int d, int& dg, int4& sal) {
        int dgl = cntL[d]; if (dgl > CAP) dgl = CAP;
        int4 c = ((const int4*)colL[d])[sl];      // 16B-aligned, conflict-free
        int eb = sl << 2;
        int nd = n0 + d;
        int self = (nd < N) ? nd : 0;
        sal.x = (eb + 0 < dgl) ? c.x : self;
        sal.y = (eb + 1 < dgl) ? c.y : self;
        sal.z = (eb + 2 < dgl) ? c.z : self;
        sal.w = (eb + 3 < dgl) ? c.w : self;
        dg = dgl;
    };

    // sub-group g handles local nodes g, g+16, g+32, g+48
    int dg0; int4 sal0;
    loadSal(g, dg0, sal0);
    float4 g0;
    g0.x = ssrc[sal0.x]; g0.y = ssrc[sal0.y];
    g0.z = ssrc[sal0.z]; g0.w = ssrc[sal0.w];

    #pragma unroll
    for (int idx = 0; idx < 4; ++idx) {
        int d = g + (idx << 4);
        int nd = n0 + d;
        int ndc = (nd < N) ? nd : 0;
        // ---- issue current node's self row + quads 0..2 ----
        uint2 hv = h2[(size_t)ndc * 16 + sl];
        int Q = dg0 > 0 ? ((dg0 + 3) >> 2) : 1;
        uint2 p0A, p0B, p0C, p0D, p1A, p1B, p1C, p1D, p2A, p2B, p2C, p2D;
        AGG_ISSUE(p0, 0)
        if (Q > 1) AGG_ISSUE(p1, 1)
        if (Q > 2) AGG_ISSUE(p2, 2)

        // ---- prep next node: sal from LDS (instant) + issue its g-gathers ----
        int dg1 = 0; int4 sal1 = make_int4(0, 0, 0, 0);
        float4 g1 = make_float4(0, 0, 0, 0);
        if (idx < 3) {
            loadSal(d + 16, dg1, sal1);
            g1.x = ssrc[sal1.x]; g1.y = ssrc[sal1.y];
            g1.z = ssrc[sal1.z]; g1.w = ssrc[sal1.w];
        }

        // ---- e/z from g0 (gathers issued one node earlier) ----
        float sdn = sdL[d];
        int eb = sl << 2;
        float e0 = (eb + 0 < dg0) ? __expf(lrelu(g0.x + sdn, 0.2f)) : 0.f;
        float e1 = (eb + 1 < dg0) ? __expf(lrelu(g0.y + sdn, 0.2f)) : 0.f;
        float e2 = (eb + 2 < dg0) ? __expf(lrelu(g0.z + sdn, 0.2f)) : 0.f;
        float e3 = (eb + 3 < dg0) ? __expf(lrelu(g0.w + sdn, 0.2f)) : 0.f;
        float z = (e0 + e1) + (e2 + e3);
        #pragma unroll
        for (int off = 1; off <= 8; off <<= 1) z += __shfl_xor(z, off, 64);
        float es = __expf(lrelu(ssL[d] + sdn, 0.2f));
        z += es;
        float4 acc;
        acc.x = es * bflo(hv.x); acc.y = es * bfhi(hv.x);
        acc.z = es * bflo(hv.y); acc.w = es * bfhi(hv.y);

        // ---- depth-3 pipelined quad loop (rotating named quads) ----
        int i = 0;
        while (true) {
            AGG_CONSUME(p0, i)
            if (i + 3 < Q) AGG_ISSUE(p0, i + 3)
            if (++i >= Q) break;
            AGG_CONSUME(p1, i)
            if (i + 3 < Q) AGG_ISSUE(p1, i + 3)
            if (++i >= Q) break;
            AGG_CONSUME(p2, i)
            if (i + 3 < Q) AGG_ISSUE(p2, i + 3)
            if (++i >= Q) break;
        }

        // epilogue — no cross-lane reduce; all 16 lanes store
        if (nd < N) {
            float inv = 1.f / z;
            float4 b4 = ((const float4*)bias)[sl];
            float4 v;
            v.x = acc.x * inv + b4.x; v.y = acc.y * inv + b4.y;
            v.z = acc.z * inv + b4.z; v.w = acc.w * inv + b4.w;
            if (mode == 0) {
                ((float4*)out)[(size_t)nd * 16 + sl] = v;
                s1.x += v.x; s1.y += v.y; s1.z += v.z; s1.w += v.w;
                s2.x += v.x * v.x; s2.y += v.y * v.y;
                s2.z += v.z * v.z; s2.w += v.w * v.w;
            } else {
                float4 xv = ((const float4*)x)[(size_t)nd * 16 + sl];
                v.x = 0.5f * (xv.x + v.x); v.y = 0.5f * (xv.y + v.y);
                v.z = 0.5f * (xv.z + v.z); v.w = 0.5f * (xv.w + v.w);
                ((float4*)out)[(size_t)nd * 16 + sl] = v;
            }
        }
        // shift node pipeline
        dg0 = dg1; sal0 = sal1; g0 = g1;
    }
    if (mode == 0) {
        int c = sl * 4;       // block-level epilogue only: 16 ops/thread once per block
        atomicAdd(&sbn1[c + 0], s1.x); atomicAdd(&sbn1[c + 1], s1.y);
        atomicAdd(&sbn1[c + 2], s1.z); atomicAdd(&sbn1[c + 3], s1.w);
        atomicAdd(&sbn2[c + 0], s2.x); atomicAdd(&sbn2[c + 1], s2.y);
        atomicAdd(&sbn2[c + 2], s2.z); atomicAdd(&sbn2[c + 3], s2.w);
        __syncthreads();
        if (tid < D) {
            atomicAdd(&bn_sum[tid], sbn1[tid]);
            atomicAdd(&bn_sumsq[tid], sbn2[tid]);
        }
    }
}

extern "C" void kernel_launch(void* const* d_in, const int* in_sizes, int n_in,
                              void* d_out, int out_size, void* d_ws, size_t ws_size,
                              hipStream_t stream) {
    const float* x     = (const float*)d_in[0];
    const float* W1    = (const float*)d_in[1];
    const float* as1   = (const float*)d_in[2];
    const float* ad1   = (const float*)d_in[3];
    const float* b1    = (const float*)d_in[4];
    const float* gamma = (const float*)d_in[5];
    const float* beta  = (const float*)d_in[6];
    const float* W2    = (const float*)d_in[7];
    const float* as2   = (const float*)d_in[8];
    const float* ad2   = (const float*)d_in[9];
    const float* b2    = (const float*)d_in[10];
    const int*   ei    = (const int*)d_in[11];
    int N = in_sizes[0] / D;
    int E = in_sizes[11] / 2;
    float* out = (float*)d_out;          // layer-1 output buffer (fp32), then final

    float* ws = (float*)d_ws;
    unsigned* hb = (unsigned*)ws;                 // bf16-packed h: N*32 uints (12.8MB)
    float* ssrc = (float*)(hb + (size_t)N * 32);
    float* sdst = ssrc + N;
    int* binp   = (int*)(sdst + N);               // NBINMAX bin totals (memset)
    float* bn   = (float*)(binp + NBINMAX);       // 128: sum(64) | sumsq(64) (memset, contiguous)
    uint4* wt1  = (uint4*)(bn + 128);             // 512 uint4 = 8KB MFMA-packed W1
    uint4* wt2  = wt1 + 512;                      // 8KB MFMA-packed W2
    unsigned* binned = (unsigned*)(wt2 + 512);    // nb*BCAP packed edges (~9.6MB, in ws:
                                                  // must SURVIVE until agg2 — no d_out alias)

    int nb = (N + NPB - 1) >> 6;                  // 1563 bins for N=100K
    int BCAP = E / nb + (E / nb) / 4 + 256;       // avg + 25% + slack (~16 sigma)

    dim3 blk(256);

    // zero bin totals + bn in one async memset
    hipMemsetAsync(binp, 0, NBINMAX * 4 + 512, stream);

    // ---- prep: pack W1/W2 into MFMA fragment tables (8KB each) ----
    k_wprep<<<4, blk, 0, stream>>>(W1, W2, wt1, wt2);

    // ---- pass 1: bin edges (NBB=256) fused with layer-1 MFMA mm ----
    k_bin_mm1<<<2048, blk, 0, stream>>>(ei, E, binp, binned, BCAP,
                                        x, wt1, as1, ad1, hb, ssrc, sdst, N);

    // ---- layer 1 aggregate (in-LDS CSR, single-pass build) ----
    k_agg<<<nb, blk, 0, stream>>>(binned, binp, BCAP, ssrc, sdst, hb, b1,
                                  nullptr, out, bn, bn + 64, 0, N);

    // ---- layer 2 (MFMA mm, 1568 blocks -> ~1 tile/wave; BN folded) ----
    k_mm_att<<<1568, blk, 0, stream>>>(out, wt2, as2, ad2, bn, bn + 64, gamma, beta,
                                       hb, ssrc, sdst, N);
    k_agg<<<nb, blk, 0, stream>>>(binned, binp, BCAP, ssrc, sdst, hb, b2,
                                  x, out, bn, bn + 64, 1, N);
}